// Round 9
// baseline (505.024 us; speedup 1.0000x reference)
//
#include <hip/hip_runtime.h>
#include <hip/hip_bf16.h>

// ---------------------------------------------------------------------------
// SFMCNN: conv1 MFMA im2col (v3b); conv2 v2: full-image 64x64-wave-tile MFMA
// GEMM (0.5 LDS reads/MFMA), conflict-free swizzle slot=(q+(row>>1))&3,
// masked async16 staging, fused pool+S3; conv3 same structure w/ fixed
// swizzle. FC LDS-free bf16 MFMA K-split.
//
// ws layout (float offsets): unchanged.
//   p1u  [0, 8306688)          bf16 (3,128,26,26,64) halo-baked; h3bf aliases
//   p2u  [8306688, +4816896)   bf16 (3,128,14,14,128) halo-baked
//   S2   [13123584, +221184)   S3 [13344768, +55296)  wsq [13400064, +1344)
//   w2s  [13401408, +110592)   w3s [13512000, +442368)
//   part [13954368, +6193152)  part2 [20147520, +102400)
// ---------------------------------------------------------------------------

static const size_t OFF_P2CL = 8306688;
static const size_t OFF_S2   = 13123584;
static const size_t OFF_S3   = 13344768;
static const size_t OFF_WSQ  = 13400064;
static const size_t OFF_W2S  = 13401408;
static const size_t OFF_W3S  = 13512000;
static const size_t OFF_PART = 13954368;
static const size_t OFF_PART2= 20147520;

typedef short bf16x8 __attribute__((ext_vector_type(8)));
typedef float f32x4 __attribute__((ext_vector_type(4)));

__device__ __forceinline__ unsigned short f2bf(float f) {
    union { float f; unsigned u; } v; v.f = f;
    unsigned r = (v.u + 0x7FFFu + ((v.u >> 16) & 1u)) >> 16;
    return (unsigned short)r;
}
__device__ __forceinline__ float bf2f(unsigned short h) {
    union { unsigned u; float f; } v; v.u = ((unsigned)h) << 16;
    return v.f;
}
__device__ __forceinline__ unsigned pkbf(float a, float b) {
    union { __hip_bfloat162 h2; unsigned u; } c;
    c.h2 = __float22bfloat162_rn(make_float2(a, b));
    return c.u;
}
__device__ __forceinline__ void async16(void* lds, const void* g) {
    __builtin_amdgcn_global_load_lds(
        (const __attribute__((address_space(1))) unsigned*)g,
        (__attribute__((address_space(3))) unsigned*)lds, 16, 0, 0);
}

// ------------------------- prep: reorders + wsq + S3 zero ------------------
__global__ __launch_bounds__(256) void prep_kernel(
        const float* __restrict__ W2, const float* __restrict__ W3,
        unsigned short* __restrict__ w2s, unsigned short* __restrict__ w3s,
        float* __restrict__ wsq, float* __restrict__ S3) {
    int gid = blockIdx.x * 256 + threadIdx.x;
#pragma unroll
    for (int k = 0; k < 2; ++k) {
        int e = gid * 2 + k;
        int t = e / 73728, r = e % 73728;
        int kk = r / 8192; r %= 8192;
        int co = r / 64, ci = r % 64;
        w2s[e] = f2bf(W2[(size_t)(t * 128 + co) * 576 + ci * 9 + kk]);
    }
#pragma unroll
    for (int k = 0; k < 8; ++k) {
        int e = gid * 8 + k;
        int t = e / 294912, r = e % 294912;
        int kk = r / 32768; r %= 32768;
        int co = r / 128, ci = r % 128;
        w3s[e] = f2bf(W3[(size_t)(t * 256 + co) * 1152 + ci * 9 + kk]);
    }
    if (gid < 55296) S3[gid] = 0.f;
    if (gid < 1152) {
        int t = gid / 384, r = gid % 384;
        if (r < 128) {
            const float* w = W2 + (size_t)(t * 128 + r) * 576; float s = 0.f;
            for (int k = 0; k < 576; ++k) { float v = bf2f(f2bf(w[k])); s += v * v; }
            wsq[192 + t * 128 + r] = s;
        } else {
            int c = r - 128;
            const float* w = W3 + (size_t)(t * 256 + c) * 1152; float s = 0.f;
            for (int k = 0; k < 1152; ++k) { float v = bf2f(f2bf(w[k])); s += v * v; }
            wsq[576 + t * 256 + c] = s;
        }
    }
}

// ------------------------- conv1 v3b: direct-tap MFMA, tile epilogue -------
__global__ __launch_bounds__(576) void conv1_kernel(
        const float* __restrict__ x, const float* __restrict__ W1,
        const float* __restrict__ triw, const float* __restrict__ crb,
        const float* __restrict__ alp,
        unsigned short* __restrict__ p1u, float* __restrict__ S2) {
    __shared__ unsigned short simgbf[16 * 56];
    __shared__ unsigned short sB[64 * 40];
    __shared__ float swq[64];
    __shared__ float srs[16 * 48];
    __shared__ float sxq[12 * 48];
    __shared__ float swt[9 * 512];

    int bi = blockIdx.x;
    int qv = blockIdx.y;
    int t = bi / 128, b = bi % 128;
    int tid = threadIdx.x;
    const float* xim = x + (size_t)(b * 3 + t) * 2304;
    int r0 = 12 * qv;

    for (int idx = tid; idx < 832; idx += 576) {
        int rl = idx / 52, cc = idx % 52;
        int y = r0 + rl - 2, xx = cc - 2;
        float v = (y >= 0 && y < 48 && xx >= 0 && xx < 48) ? xim[y * 48 + xx] : 0.f;
        simgbf[rl * 56 + cc] = f2bf(v);
    }
    if (tid < 64) {
        const float* wp = W1 + (size_t)t * 1600 + tid * 25;
        unsigned short tmp[40];
        float s = 0.f;
#pragma unroll
        for (int k = 0; k < 25; ++k) {
            unsigned short u = f2bf(wp[k]);
            tmp[k] = u; float v = bf2f(u); s += v * v;
        }
#pragma unroll
        for (int k = 25; k < 40; ++k) tmp[k] = 0;
        uint4* bp = (uint4*)&sB[tid * 40];
#pragma unroll
        for (int j = 0; j < 5; ++j) {
            uint4 v4;
            v4.x = (unsigned)tmp[8 * j] | ((unsigned)tmp[8 * j + 1] << 16);
            v4.y = (unsigned)tmp[8 * j + 2] | ((unsigned)tmp[8 * j + 3] << 16);
            v4.z = (unsigned)tmp[8 * j + 4] | ((unsigned)tmp[8 * j + 5] << 16);
            v4.w = (unsigned)tmp[8 * j + 6] | ((unsigned)tmp[8 * j + 7] << 16);
            bp[j] = v4;
        }
        swq[tid] = s;
    }
    __syncthreads();

    for (int idx = tid; idx < 768; idx += 576) {
        int i = idx / 48, ox = idx % 48;
        const unsigned short* r = &simgbf[i * 56 + ox];
        float s = 0.f;
#pragma unroll
        for (int j = 0; j < 5; ++j) { float v = bf2f(r[j]); s += v * v; }
        srs[idx] = s;
    }
    __syncthreads();
    {
        int oy = tid / 48, ox = tid % 48;
        float s = 0.f;
#pragma unroll
        for (int i = 0; i < 5; ++i) s += srs[(oy + i) * 48 + ox];
        sxq[tid] = s;
    }
    __syncthreads();

    int w = tid >> 6, l = tid & 63;
    int lm = l & 15, q = l >> 4;

    bf16x8 bF[4];
#pragma unroll
    for (int nt = 0; nt < 4; ++nt)
        bF[nt] = *(const bf16x8*)(&sB[(nt * 16 + lm) * 40 + q * 8]);
    float wqv[4];
#pragma unroll
    for (int nt = 0; nt < 4; ++nt) wqv[nt] = swq[nt * 16 + lm];

    f32x4 zz; zz[0] = 0.f; zz[1] = 0.f; zz[2] = 0.f; zz[3] = 0.f;
    f32x4 acc[4][4];
#pragma unroll
    for (int mt = 0; mt < 4; ++mt) {
        int tile = w * 4 + mt;
        int oy = (tile / 12) * 4 + (lm >> 2);
        int ox = (tile % 12) * 4 + (lm & 3);
        const unsigned short* pp = &simgbf[oy * 56 + ox];
        unsigned short tap[8];
#pragma unroll
        for (int j = 0; j < 8; ++j) {
            int k = q * 8 + j;
            int ky = (k * 13) >> 6;
            int kx = k - ky * 5;
            tap[j] = (k < 25) ? pp[ky * 56 + kx] : (unsigned short)0;
        }
        union { bf16x8 v; unsigned u[4]; } aF;
#pragma unroll
        for (int j2 = 0; j2 < 4; ++j2)
            aF.u[j2] = (unsigned)tap[2 * j2] | ((unsigned)tap[2 * j2 + 1] << 16);
#pragma unroll
        for (int nt = 0; nt < 4; ++nt)
            acc[mt][nt] = __builtin_amdgcn_mfma_f32_16x16x32_bf16(aF.v, bF[nt], zz, 0, 0, 0);
    }

    float tw = triw[t * 3 + 0], itw = 1.f / tw;
    float cb = crb[t * 3 + 0];
    float al = alp[t * 2 + 0];
    float apw[4] = {al * al * al * 0.25f, al * al * 0.25f, al * 0.25f, 0.25f};
    size_t imgbase = (size_t)bi * 43264;
    float* swt_w = &swt[w * 512];
    int qa = q & 1;

#pragma unroll
    for (int mt = 0; mt < 4; ++mt) {
        int tile = w * 4 + mt;
        int ty = tile / 12, tx = tile % 12;
        f32x4 xq = *(const f32x4*)&sxq[(ty * 4 + q) * 48 + tx * 4];
#pragma unroll
        for (int nt = 0; nt < 4; ++nt) {
            float hw[4];
#pragma unroll
            for (int r = 0; r < 4; ++r) {
                float d = fmaf(-2.f, acc[mt][nt][r], xq[r]) + wqv[nt];
                d = fminf(fmaxf(d, 0.f), tw);
                float h = 1.f - d * itw;
                h = (h >= cb) ? h : 0.f;
                hw[r] = h * apw[qa * 2 + (r & 1)];
            }
            swt_w[(q * 2 + 0) * 64 + nt * 16 + lm] = hw[0] + hw[1];
            swt_w[(q * 2 + 1) * 64 + nt * 16 + lm] = hw[2] + hw[3];
        }
        int cell = l >> 4;
        int py = cell >> 1, px = cell & 1;
        int ch0 = (l & 15) * 4;
        f32x4 v0 = *(const f32x4*)&swt_w[(py * 4 + px) * 64 + ch0];
        f32x4 v1 = *(const f32x4*)&swt_w[((2 * py + 1) * 2 + px) * 64 + ch0];
        f32x4 s;
#pragma unroll
        for (int j = 0; j < 4; ++j) s[j] = v0[j] + v1[j];
        uint2 uv; uv.x = pkbf(s[0], s[1]); uv.y = pkbf(s[2], s[3]);
        int py_g = qv * 6 + ty * 2 + py;
        int px_g = tx * 2 + px;
        int cell_g = (py_g + 1) * 26 + px_g + 1;
        *(uint2*)(p1u + imgbase + (size_t)cell_g * 64 + ch0) = uv;
        float r0v = bf2f((unsigned short)(uv.x & 0xFFFFu));
        float r1v = bf2f((unsigned short)(uv.x >> 16));
        float r2v = bf2f((unsigned short)(uv.y & 0xFFFFu));
        float r3v = bf2f((unsigned short)(uv.y >> 16));
        float s2p = r0v * r0v + r1v * r1v + r2v * r2v + r3v * r3v;
#pragma unroll
        for (int m2 = 1; m2 < 16; m2 <<= 1) s2p += __shfl_xor(s2p, m2, 64);
        if ((l & 15) == 0) S2[(size_t)bi * 576 + py_g * 24 + px_g] = s2p;
    }

    if (tid < 200) {
        int e = qv * 200 + tid;
        int bc = e >> 3, c8 = e & 7;
        int cell;
        if (bc < 26) cell = bc;
        else if (bc < 52) cell = 650 + (bc - 26);
        else { int r = bc - 52; cell = (1 + (r >> 1)) * 26 + ((r & 1) * 25); }
        uint4 z; z.x = 0; z.y = 0; z.z = 0; z.w = 0;
        *(uint4*)(p1u + imgbase + (size_t)cell * 64 + c8 * 8) = z;
    }
}

// ------------------------- conv2 v2: full-image 64x64-wave-tile MFMA -------
// grid (384 images, 2 co-halves), block 576 = 9 waves. M=576 (36 4x4-blocks),
// N=64, K=2ks x 9kk x 32ci. Weights staged in 2 groups (kk 0-3, 4-8).
// Swizzle slot=(q+(row>>1))&3 -> conflict-free b128 reads. Fused pool+S3.
// LDS: img [0,43264); w [43264,63744); sS 63744 (676f); sxqm 66448 (576f);
//      swq 68752 (64f). total 69008 B -> 2 blocks/CU.
__global__ __launch_bounds__(576, 5) void conv2_kernel(
        const unsigned short* __restrict__ p1u, const unsigned short* __restrict__ w2s,
        const float* __restrict__ S2, const float* __restrict__ triw,
        const float* __restrict__ crb, const float* __restrict__ alp,
        const float* __restrict__ wsq, unsigned short* __restrict__ p2u,
        float* __restrict__ S3) {
    extern __shared__ char sm[];
    float* sS   = (float*)(sm + 63744);
    float* sxqm = (float*)(sm + 66448);
    float* swq  = (float*)(sm + 68752);

    int i = blockIdx.x;
    int t = i / 128;
    int co0 = blockIdx.y * 64;
    int tid = threadIdx.x;
    int w = tid >> 6, l = tid & 63;
    int lm = l & 15, q = l >> 4;

    for (int e = tid; e < 676; e += 576) {
        int yy = e / 26, xx = e % 26;
        sS[e] = (yy >= 1 && yy <= 24 && xx >= 1 && xx <= 24)
                    ? S2[(size_t)i * 576 + (yy - 1) * 24 + (xx - 1)] : 0.f;
    }
    if (tid < 64) swq[tid] = wsq[192 + t * 128 + co0 + tid];
    __syncthreads();
    {
        int oy = tid / 24, ox = tid % 24;    // 576 exactly
        float s = 0.f;
#pragma unroll
        for (int ky = 0; ky < 3; ++ky)
#pragma unroll
            for (int kx = 0; kx < 3; ++kx) s += sS[(oy + ky) * 26 + ox + kx];
        sxqm[tid] = s;
    }

    int posA[4];
#pragma unroll
    for (int mt = 0; mt < 4; ++mt) {
        int tl = w * 4 + mt;
        posA[mt] = ((tl / 6) * 4 + (lm >> 2)) * 26 + (tl % 6) * 4 + (lm & 3);
    }

    f32x4 zz; zz[0] = 0.f; zz[1] = 0.f; zz[2] = 0.f; zz[3] = 0.f;
    f32x4 acc[4][4];
#pragma unroll
    for (int a = 0; a < 4; ++a)
#pragma unroll
        for (int bb = 0; bb < 4; ++bb) acc[a][bb] = zz;

    for (int ks = 0; ks < 2; ++ks) {
        __syncthreads();
        // img: 676 cells x 4 chunks = 2704 (masked tail)
#pragma unroll
        for (int it = 0; it < 5; ++it) {
            int L = it * 576 + tid;
            if (L < 2704) {
                int cell = L >> 2, pos = L & 3;
                int c = (pos - (cell >> 1)) & 3;
                const unsigned short* g = p1u + ((size_t)i * 676 + cell) * 64
                                          + ks * 32 + c * 8;
                async16(sm + ((L & ~63) << 4), g);
            }
        }
        // weights group 0: kk 0..3 -> 256 rows x 4 = 1024 chunks
#pragma unroll
        for (int it = 0; it < 2; ++it) {
            int L = it * 576 + tid;
            if (L < 1024) {
                int row = L >> 2, pos = L & 3;
                int c = (pos - (row >> 1)) & 3;
                int kk = row >> 6, n = row & 63;
                const unsigned short* g = w2s + ((size_t)(t * 9 + kk) * 128 + co0 + n) * 64
                                          + ks * 32 + c * 8;
                async16(sm + 43264 + ((L & ~63) << 4), g);
            }
        }
        __builtin_amdgcn_s_waitcnt(0);
        __syncthreads();
#pragma unroll
        for (int kkl = 0; kkl < 4; ++kkl) {          // kk 0..3
            int kof = (kkl / 3) * 26 + (kkl % 3);
            bf16x8 bF[4];
#pragma unroll
            for (int nt = 0; nt < 4; ++nt) {
                int r = kkl * 64 + nt * 16 + lm;
                bF[nt] = *(const bf16x8*)(sm + 43264 + r * 64 + ((q + (r >> 1)) & 3) * 16);
            }
#pragma unroll
            for (int mt = 0; mt < 4; ++mt) {
                int ar = posA[mt] + kof;
                bf16x8 aF = *(const bf16x8*)(sm + ar * 64 + ((q + (ar >> 1)) & 3) * 16);
#pragma unroll
                for (int nt = 0; nt < 4; ++nt)
                    acc[mt][nt] = __builtin_amdgcn_mfma_f32_16x16x32_bf16(aF, bF[nt], acc[mt][nt], 0, 0, 0);
            }
        }
        __syncthreads();
        // weights group 1: kk 4..8 -> 320 rows x 4 = 1280 chunks
#pragma unroll
        for (int it = 0; it < 3; ++it) {
            int L = it * 576 + tid;
            if (L < 1280) {
                int row = L >> 2, pos = L & 3;
                int c = (pos - (row >> 1)) & 3;
                int kk = 4 + (row >> 6), n = row & 63;
                const unsigned short* g = w2s + ((size_t)(t * 9 + kk) * 128 + co0 + n) * 64
                                          + ks * 32 + c * 8;
                async16(sm + 43264 + ((L & ~63) << 4), g);
            }
        }
        __builtin_amdgcn_s_waitcnt(0);
        __syncthreads();
#pragma unroll
        for (int kkl = 0; kkl < 5; ++kkl) {          // kk 4..8
            int kk = 4 + kkl;
            int kof = (kk / 3) * 26 + (kk % 3);
            bf16x8 bF[4];
#pragma unroll
            for (int nt = 0; nt < 4; ++nt) {
                int r = kkl * 64 + nt * 16 + lm;
                bF[nt] = *(const bf16x8*)(sm + 43264 + r * 64 + ((q + (r >> 1)) & 3) * 16);
            }
#pragma unroll
            for (int mt = 0; mt < 4; ++mt) {
                int ar = posA[mt] + kof;
                bf16x8 aF = *(const bf16x8*)(sm + ar * 64 + ((q + (ar >> 1)) & 3) * 16);
#pragma unroll
                for (int nt = 0; nt < 4; ++nt)
                    acc[mt][nt] = __builtin_amdgcn_mfma_f32_16x16x32_bf16(aF, bF[nt], acc[mt][nt], 0, 0, 0);
            }
        }
    }

    float tw = triw[t * 3 + 1], itw = 1.f / tw, cb = crb[t * 3 + 1], al = alp[t * 2 + 1];
    float apw[4] = {al * al * al * 0.25f, al * al * 0.25f, al * 0.25f, 0.25f};
    int qa = q & 1;

#pragma unroll
    for (int mt = 0; mt < 4; ++mt) {
        int tl = w * 4 + mt;
        int ty = tl / 6, tx = tl % 6;
        f32x4 xq = *(const f32x4*)(sxqm + (ty * 4 + q) * 24 + tx * 4);
        float s3loc[2] = {0.f, 0.f};
        unsigned short pu[4][2];
#pragma unroll
        for (int nt = 0; nt < 4; ++nt) {
            float wq = swq[nt * 16 + lm];
            float hw[4];
#pragma unroll
            for (int r = 0; r < 4; ++r) {
                float d = fmaf(-2.f, acc[mt][nt][r], xq[r]) + wq;
                d = fminf(fmaxf(d, 0.f), tw);
                float hv = 1.f - d * itw;
                hv = (hv >= cb) ? hv : 0.f;
                hw[r] = hv * apw[qa * 2 + (r & 1)];
            }
            float ph0 = hw[0] + hw[1], ph1 = hw[2] + hw[3];
            float p0 = ph0 + __shfl_xor(ph0, 16, 64);
            float p1 = ph1 + __shfl_xor(ph1, 16, 64);
            unsigned short u0 = f2bf(p0), u1 = f2bf(p1);
            float v0 = bf2f(u0), v1 = bf2f(u1);
            s3loc[0] += v0 * v0;
            s3loc[1] += v1 * v1;
            pu[nt][0] = u0; pu[nt][1] = u1;
        }
#pragma unroll
        for (int m2 = 1; m2 < 16; m2 <<= 1) {
            s3loc[0] += __shfl_xor(s3loc[0], m2, 64);
            s3loc[1] += __shfl_xor(s3loc[1], m2, 64);
        }
        if ((q & 1) == 0) {
            int py = ty * 2 + (q >> 1);
            int px0 = tx * 2;
            int cell = (py + 1) * 14 + px0 + 1;
#pragma unroll
            for (int nt = 0; nt < 4; ++nt) {
                p2u[((size_t)i * 196 + cell) * 128 + co0 + nt * 16 + lm] = pu[nt][0];
                p2u[((size_t)i * 196 + cell + 1) * 128 + co0 + nt * 16 + lm] = pu[nt][1];
            }
            if (lm == 0) {
                atomicAdd(&S3[(size_t)i * 144 + py * 12 + px0], s3loc[0]);
                atomicAdd(&S3[(size_t)i * 144 + py * 12 + px0 + 1], s3loc[1]);
            }
        }
    }

    // border zeros: 52 cells x 8 chunks (this co-half)
    if (tid < 416) {
        int bc = tid >> 3, c8 = tid & 7;
        int cell;
        if (bc < 14) cell = bc;
        else if (bc < 28) cell = 182 + (bc - 14);
        else { int r = bc - 28; cell = (1 + (r >> 1)) * 14 + ((r & 1) * 13); }
        uint4 z; z.x = 0; z.y = 0; z.z = 0; z.w = 0;
        *(uint4*)(p2u + ((size_t)i * 196 + cell) * 128 + co0 + c8 * 8) = z;
    }
}

// ------------------------- conv3: 2-img MFMA GEMM -> h3 bf16 ---------------
__global__ __launch_bounds__(576, 5) void conv3_kernel(
        const unsigned short* __restrict__ p2u, const unsigned short* __restrict__ w3s,
        const float* __restrict__ S3, const float* __restrict__ triw,
        const float* __restrict__ crb, const float* __restrict__ wsq,
        unsigned short* __restrict__ h3bf) {
    extern __shared__ char sm[];
    float* sS3   = (float*)(sm + 64512);
    float* sxq3  = (float*)(sm + 66080);
    float* wsqh3 = (float*)(sm + 67232);

    int g = blockIdx.x;
    int i0 = g * 2;
    int t = i0 / 128;
    int co0 = blockIdx.y * 64;
    int tid = threadIdx.x;
    int w = tid >> 6, l = tid & 63;
    int lm = l & 15, q = l >> 4;

    for (int e = tid; e < 392; e += 576) {
        int il = e / 196, cl = e % 196;
        int yy = cl / 14, xx = cl % 14;
        sS3[e] = (yy >= 1 && yy <= 12 && xx >= 1 && xx <= 12)
                     ? S3[(size_t)(i0 + il) * 144 + (yy - 1) * 12 + (xx - 1)] : 0.f;
    }
    if (tid < 64) wsqh3[tid] = wsq[576 + t * 256 + co0 + tid];
    __syncthreads();
    if (tid < 288) {
        int il = tid / 144, s = tid % 144;
        int oy = s / 12, ox = s % 12;
        float sum = 0.f;
#pragma unroll
        for (int ky = 0; ky < 3; ++ky)
#pragma unroll
            for (int kx = 0; kx < 3; ++kx)
                sum += sS3[il * 196 + (oy + ky) * 14 + (ox + kx)];
        sxq3[tid] = sum;
    }

    int posA[2], img_l[2], s0a[2];
#pragma unroll
    for (int mt = 0; mt < 2; ++mt) {
        int tb = w * 32 + mt * 16;
        int il = tb / 144, s0 = tb % 144;
        int s = s0 + lm;
        posA[mt] = il * 196 + (s / 12) * 14 + (s % 12);
        img_l[mt] = il; s0a[mt] = s0;
    }

    f32x4 zz; zz[0] = 0.f; zz[1] = 0.f; zz[2] = 0.f; zz[3] = 0.f;
    f32x4 acc[2][4];
#pragma unroll
    for (int a = 0; a < 2; ++a)
#pragma unroll
        for (int bb = 0; bb < 4; ++bb) acc[a][bb] = zz;

    for (int ks = 0; ks < 4; ++ks) {
        __syncthreads();
#pragma unroll
        for (int it = 0; it < 3; ++it) {
            int L = it * 576 + tid;
            if (L < 1568) {
                int cell = L >> 2, pos = L & 3;
                int il = cell / 196, cl = cell - il * 196;
                int c = (pos - (cell >> 1)) & 3;
                const unsigned short* gp = p2u + ((size_t)(i0 + il) * 196 + cl) * 128
                                           + ks * 32 + c * 8;
                async16(sm + ((L & ~63) << 4), gp);
            }
        }
#pragma unroll
        for (int it = 0; it < 4; ++it) {
            int L = it * 576 + tid;
            int row = L >> 2, pos = L & 3;
            int c = (pos - (row >> 1)) & 3;
            int kk = row >> 6, n = row & 63;
            const unsigned short* gp = w3s + ((size_t)(t * 9 + kk) * 256 + co0 + n) * 128
                                       + ks * 32 + c * 8;
            async16(sm + 27648 + ((L & ~63) << 4), gp);
        }
        __builtin_amdgcn_s_waitcnt(0);
        __syncthreads();
#pragma unroll
        for (int kk = 0; kk < 9; ++kk) {
            int kof = (kk / 3) * 14 + (kk % 3);
            bf16x8 aF3[2], bF3[4];
#pragma unroll
            for (int mt = 0; mt < 2; ++mt) {
                int ci = posA[mt] + kof;
                aF3[mt] = *(const bf16x8*)(sm + ci * 64 + ((q + (ci >> 1)) & 3) * 16);
            }
#pragma unroll
            for (int nt = 0; nt < 4; ++nt) {
                int r = kk * 64 + nt * 16 + lm;
                bF3[nt] = *(const bf16x8*)(sm + 27648 + r * 64 + ((q + (r >> 1)) & 3) * 16);
                acc[0][nt] = __builtin_amdgcn_mfma_f32_16x16x32_bf16(aF3[0], bF3[nt], acc[0][nt], 0, 0, 0);
                acc[1][nt] = __builtin_amdgcn_mfma_f32_16x16x32_bf16(aF3[1], bF3[nt], acc[1][nt], 0, 0, 0);
            }
        }
    }
    __syncthreads();

    float tw = triw[t * 3 + 2], itw = 1.f / tw, cb = crb[t * 3 + 2];
    float* tile = (float*)(sm + w * 1280);
#pragma unroll
    for (int mt = 0; mt < 2; ++mt) {
        int il = img_l[mt], s0 = s0a[mt];
        int bidx = (i0 + il) - t * 128;
        unsigned short* gbase = h3bf + (size_t)bidx * 110592 + (size_t)t * 36864;
#pragma unroll
        for (int nt = 0; nt < 4; ++nt) {
            float wq = wsqh3[nt * 16 + lm];
#pragma unroll
            for (int r = 0; r < 4; ++r) {
                float d = sxq3[il * 144 + s0 + q * 4 + r] - 2.f * acc[mt][nt][r] + wq;
                d = fminf(fmaxf(d, 0.f), tw);
                float hv = 1.f - d * itw;
                hv = (hv >= cb) ? hv : 0.f;
                tile[lm * 20 + q * 4 + r] = hv;
            }
            f32x4 v = *(const f32x4*)(tile + (l >> 2) * 20 + (l & 3) * 4);
            uint2 uv; uv.x = pkbf(v[0], v[1]); uv.y = pkbf(v[2], v[3]);
            *(uint2*)(gbase + (size_t)(co0 + nt * 16 + (l >> 2)) * 144 + s0 + (l & 3) * 4) = uv;
        }
    }
}

// ------------------------- FC: LDS-free bf16 MFMA K-split ------------------
__global__ __launch_bounds__(512) void fc_kernel(
        const unsigned short* __restrict__ h3bf, const float* __restrict__ fcw,
        float* __restrict__ part) {
    int kb = blockIdx.x;
    int f0 = kb * 256;
    int tid = threadIdx.x;
    int w = tid >> 6, l = tid & 63;
    int lm = l & 15, q = l >> 4;

    const unsigned short* abase = h3bf + (size_t)(w * 16 + lm) * 110592 + f0 + q * 8;
    const float* brow[7];
#pragma unroll
    for (int nt = 0; nt < 7; ++nt) {
        int n = nt * 16 + lm;
        if (n > 99) n = 99;
        brow[nt] = fcw + (size_t)n * 110592 + f0 + q * 8;
    }

    f32x4 zz; zz[0] = 0.f; zz[1] = 0.f; zz[2] = 0.f; zz[3] = 0.f;
    f32x4 acc[7];
#pragma unroll
    for (int nt = 0; nt < 7; ++nt) acc[nt] = zz;

#pragma unroll 2
    for (int kc = 0; kc < 8; ++kc) {
        bf16x8 aF = *(const bf16x8*)(abase + kc * 32);
#pragma unroll
        for (int nt = 0; nt < 7; ++nt) {
            f32x4 b0 = *(const f32x4*)(brow[nt] + kc * 32);
            f32x4 b1 = *(const f32x4*)(brow[nt] + kc * 32 + 4);
            union { bf16x8 v; unsigned u[4]; } bF;
            bF.u[0] = pkbf(b0[0], b0[1]);
            bF.u[1] = pkbf(b0[2], b0[3]);
            bF.u[2] = pkbf(b1[0], b1[1]);
            bF.u[3] = pkbf(b1[2], b1[3]);
            acc[nt] = __builtin_amdgcn_mfma_f32_16x16x32_bf16(aF, bF.v, acc[nt], 0, 0, 0);
        }
    }

    float* pb = part + (size_t)kb * 14336;
#pragma unroll
    for (int nt = 0; nt < 7; ++nt)
#pragma unroll
        for (int r = 0; r < 4; ++r)
            pb[(w * 16 + q * 4 + r) * 112 + nt * 16 + lm] = acc[nt][r];
}

__global__ __launch_bounds__(256) void fc_red1_kernel(const float* __restrict__ part,
                                                      float* __restrict__ part2) {
    int c = blockIdx.x;
    int gid = blockIdx.y * 256 + threadIdx.x;
    if (gid >= 12800) return;
    const float* p = part + (size_t)(c * 54) * 14336 + (gid / 100) * 112 + gid % 100;
    float s = 0.f;
#pragma unroll 6
    for (int kb = 0; kb < 54; ++kb) s += p[(size_t)kb * 14336];
    part2[c * 12800 + gid] = s;
}

__global__ __launch_bounds__(256) void fc_red2_kernel(const float* __restrict__ part2,
                                                      const float* __restrict__ fcb,
                                                      float* __restrict__ out) {
    int gid = blockIdx.x * 256 + threadIdx.x;
    if (gid >= 12800) return;
    float s = fcb[gid % 100];
#pragma unroll
    for (int c = 0; c < 8; ++c) s += part2[c * 12800 + gid];
    out[gid] = s;
}

// ---------------------------------------------------------------------------
extern "C" void kernel_launch(void* const* d_in, const int* in_sizes, int n_in,
                              void* d_out, int out_size, void* d_ws, size_t ws_size,
                              hipStream_t stream) {
    const float* x    = (const float*)d_in[0];
    const float* W1   = (const float*)d_in[1];
    const float* W2   = (const float*)d_in[2];
    const float* W3   = (const float*)d_in[3];
    const float* triw = (const float*)d_in[4];
    const float* crb  = (const float*)d_in[5];
    const float* alp  = (const float*)d_in[6];
    const float* fcw  = (const float*)d_in[7];
    const float* fcb  = (const float*)d_in[8];
    float* out = (float*)d_out;
    float* ws  = (float*)d_ws;

    unsigned short* p1u = (unsigned short*)ws;
    unsigned short* p2u = (unsigned short*)(ws + OFF_P2CL);
    float* S2  = ws + OFF_S2;
    float* S3  = ws + OFF_S3;
    float* wsq = ws + OFF_WSQ;
    unsigned short* w2s = (unsigned short*)(ws + OFF_W2S);
    unsigned short* w3s = (unsigned short*)(ws + OFF_W3S);
    float* part  = ws + OFF_PART;
    float* part2 = ws + OFF_PART2;
    unsigned short* h3bf = (unsigned short*)ws;

    hipFuncSetAttribute((const void*)conv2_kernel,
                        hipFuncAttributeMaxDynamicSharedMemorySize, 69008);
    hipFuncSetAttribute((const void*)conv3_kernel,
                        hipFuncAttributeMaxDynamicSharedMemorySize, 67488);

    prep_kernel<<<dim3(432), dim3(256), 0, stream>>>(W2, W3, w2s, w3s, wsq, S3);
    conv1_kernel<<<dim3(384, 4), dim3(576), 0, stream>>>(x, W1, triw, crb, alp, p1u, S2);
    conv2_kernel<<<dim3(384, 2), dim3(576), 69008, stream>>>(p1u, w2s, S2, triw, crb, alp, wsq, p2u, S3);
    conv3_kernel<<<dim3(192, 4), dim3(576), 67488, stream>>>(p2u, w3s, S3, triw, crb, wsq, h3bf);
    fc_kernel<<<dim3(432), dim3(512), 0, stream>>>(h3bf, fcw, part);
    fc_red1_kernel<<<dim3(8, 50), dim3(256), 0, stream>>>(part, part2);
    fc_red2_kernel<<<dim3(50), dim3(256), 0, stream>>>(part2, fcb, out);
}

// Round 10
// 376.294 us; speedup vs baseline: 1.3421x; 1.3421x over previous
//
#include <hip/hip_runtime.h>
#include <hip/hip_bf16.h>

// ---------------------------------------------------------------------------
// SFMCNN: conv1 MFMA im2col (v3b); conv2 = round-8 half-image 2-mt MFMA GEMM
// (the measured-74us no-spill structure) with the CORRECTED conflict-free
// swizzle slot=(q+(row>>1))&3 on both staging and read sides; conv3 same
// fixed swizzle (acc[2][4] fits the 102-VGPR budget). FC LDS-free bf16 MFMA.
// LESSON (r7, r9): acc tiles >32 VGPRs under __launch_bounds__(576,5) spill
// to scratch (VGPR_Count drops, WRITE_SIZE explodes). Keep acc[2][4].
//
// ws layout (float offsets): unchanged.
//   p1u  [0, 8306688)          bf16 (3,128,26,26,64) halo-baked; h3bf aliases
//   p2u  [8306688, +4816896)   bf16 (3,128,14,14,128) halo-baked
//   S2   [13123584, +221184)   S3 [13344768, +55296)  wsq [13400064, +1344)
//   w2s  [13401408, +110592)   w3s [13512000, +442368)
//   part [13954368, +6193152)  part2 [20147520, +102400)
// ---------------------------------------------------------------------------

static const size_t OFF_P2CL = 8306688;
static const size_t OFF_S2   = 13123584;
static const size_t OFF_S3   = 13344768;
static const size_t OFF_WSQ  = 13400064;
static const size_t OFF_W2S  = 13401408;
static const size_t OFF_W3S  = 13512000;
static const size_t OFF_PART = 13954368;
static const size_t OFF_PART2= 20147520;

typedef short bf16x8 __attribute__((ext_vector_type(8)));
typedef float f32x4 __attribute__((ext_vector_type(4)));

__device__ __forceinline__ unsigned short f2bf(float f) {
    union { float f; unsigned u; } v; v.f = f;
    unsigned r = (v.u + 0x7FFFu + ((v.u >> 16) & 1u)) >> 16;
    return (unsigned short)r;
}
__device__ __forceinline__ float bf2f(unsigned short h) {
    union { unsigned u; float f; } v; v.u = ((unsigned)h) << 16;
    return v.f;
}
__device__ __forceinline__ unsigned pkbf(float a, float b) {
    union { __hip_bfloat162 h2; unsigned u; } c;
    c.h2 = __float22bfloat162_rn(make_float2(a, b));
    return c.u;
}
__device__ __forceinline__ void async16(void* lds, const void* g) {
    __builtin_amdgcn_global_load_lds(
        (const __attribute__((address_space(1))) unsigned*)g,
        (__attribute__((address_space(3))) unsigned*)lds, 16, 0, 0);
}

// ------------------------- prep: reorders + wsq + S3 zero ------------------
__global__ __launch_bounds__(256) void prep_kernel(
        const float* __restrict__ W2, const float* __restrict__ W3,
        unsigned short* __restrict__ w2s, unsigned short* __restrict__ w3s,
        float* __restrict__ wsq, float* __restrict__ S3) {
    int gid = blockIdx.x * 256 + threadIdx.x;
#pragma unroll
    for (int k = 0; k < 2; ++k) {
        int e = gid * 2 + k;
        int t = e / 73728, r = e % 73728;
        int kk = r / 8192; r %= 8192;
        int co = r / 64, ci = r % 64;
        w2s[e] = f2bf(W2[(size_t)(t * 128 + co) * 576 + ci * 9 + kk]);
    }
#pragma unroll
    for (int k = 0; k < 8; ++k) {
        int e = gid * 8 + k;
        int t = e / 294912, r = e % 294912;
        int kk = r / 32768; r %= 32768;
        int co = r / 128, ci = r % 128;
        w3s[e] = f2bf(W3[(size_t)(t * 256 + co) * 1152 + ci * 9 + kk]);
    }
    if (gid < 55296) S3[gid] = 0.f;
    if (gid < 1152) {
        int t = gid / 384, r = gid % 384;
        if (r < 128) {
            const float* w = W2 + (size_t)(t * 128 + r) * 576; float s = 0.f;
            for (int k = 0; k < 576; ++k) { float v = bf2f(f2bf(w[k])); s += v * v; }
            wsq[192 + t * 128 + r] = s;
        } else {
            int c = r - 128;
            const float* w = W3 + (size_t)(t * 256 + c) * 1152; float s = 0.f;
            for (int k = 0; k < 1152; ++k) { float v = bf2f(f2bf(w[k])); s += v * v; }
            wsq[576 + t * 256 + c] = s;
        }
    }
}

// ------------------------- conv1 v3b: direct-tap MFMA, tile epilogue -------
__global__ __launch_bounds__(576) void conv1_kernel(
        const float* __restrict__ x, const float* __restrict__ W1,
        const float* __restrict__ triw, const float* __restrict__ crb,
        const float* __restrict__ alp,
        unsigned short* __restrict__ p1u, float* __restrict__ S2) {
    __shared__ unsigned short simgbf[16 * 56];
    __shared__ unsigned short sB[64 * 40];
    __shared__ float swq[64];
    __shared__ float srs[16 * 48];
    __shared__ float sxq[12 * 48];
    __shared__ float swt[9 * 512];

    int bi = blockIdx.x;
    int qv = blockIdx.y;
    int t = bi / 128, b = bi % 128;
    int tid = threadIdx.x;
    const float* xim = x + (size_t)(b * 3 + t) * 2304;
    int r0 = 12 * qv;

    for (int idx = tid; idx < 832; idx += 576) {
        int rl = idx / 52, cc = idx % 52;
        int y = r0 + rl - 2, xx = cc - 2;
        float v = (y >= 0 && y < 48 && xx >= 0 && xx < 48) ? xim[y * 48 + xx] : 0.f;
        simgbf[rl * 56 + cc] = f2bf(v);
    }
    if (tid < 64) {
        const float* wp = W1 + (size_t)t * 1600 + tid * 25;
        unsigned short tmp[40];
        float s = 0.f;
#pragma unroll
        for (int k = 0; k < 25; ++k) {
            unsigned short u = f2bf(wp[k]);
            tmp[k] = u; float v = bf2f(u); s += v * v;
        }
#pragma unroll
        for (int k = 25; k < 40; ++k) tmp[k] = 0;
        uint4* bp = (uint4*)&sB[tid * 40];
#pragma unroll
        for (int j = 0; j < 5; ++j) {
            uint4 v4;
            v4.x = (unsigned)tmp[8 * j] | ((unsigned)tmp[8 * j + 1] << 16);
            v4.y = (unsigned)tmp[8 * j + 2] | ((unsigned)tmp[8 * j + 3] << 16);
            v4.z = (unsigned)tmp[8 * j + 4] | ((unsigned)tmp[8 * j + 5] << 16);
            v4.w = (unsigned)tmp[8 * j + 6] | ((unsigned)tmp[8 * j + 7] << 16);
            bp[j] = v4;
        }
        swq[tid] = s;
    }
    __syncthreads();

    for (int idx = tid; idx < 768; idx += 576) {
        int i = idx / 48, ox = idx % 48;
        const unsigned short* r = &simgbf[i * 56 + ox];
        float s = 0.f;
#pragma unroll
        for (int j = 0; j < 5; ++j) { float v = bf2f(r[j]); s += v * v; }
        srs[idx] = s;
    }
    __syncthreads();
    {
        int oy = tid / 48, ox = tid % 48;
        float s = 0.f;
#pragma unroll
        for (int i = 0; i < 5; ++i) s += srs[(oy + i) * 48 + ox];
        sxq[tid] = s;
    }
    __syncthreads();

    int w = tid >> 6, l = tid & 63;
    int lm = l & 15, q = l >> 4;

    bf16x8 bF[4];
#pragma unroll
    for (int nt = 0; nt < 4; ++nt)
        bF[nt] = *(const bf16x8*)(&sB[(nt * 16 + lm) * 40 + q * 8]);
    float wqv[4];
#pragma unroll
    for (int nt = 0; nt < 4; ++nt) wqv[nt] = swq[nt * 16 + lm];

    f32x4 zz; zz[0] = 0.f; zz[1] = 0.f; zz[2] = 0.f; zz[3] = 0.f;
    f32x4 acc[4][4];
#pragma unroll
    for (int mt = 0; mt < 4; ++mt) {
        int tile = w * 4 + mt;
        int oy = (tile / 12) * 4 + (lm >> 2);
        int ox = (tile % 12) * 4 + (lm & 3);
        const unsigned short* pp = &simgbf[oy * 56 + ox];
        unsigned short tap[8];
#pragma unroll
        for (int j = 0; j < 8; ++j) {
            int k = q * 8 + j;
            int ky = (k * 13) >> 6;
            int kx = k - ky * 5;
            tap[j] = (k < 25) ? pp[ky * 56 + kx] : (unsigned short)0;
        }
        union { bf16x8 v; unsigned u[4]; } aF;
#pragma unroll
        for (int j2 = 0; j2 < 4; ++j2)
            aF.u[j2] = (unsigned)tap[2 * j2] | ((unsigned)tap[2 * j2 + 1] << 16);
#pragma unroll
        for (int nt = 0; nt < 4; ++nt)
            acc[mt][nt] = __builtin_amdgcn_mfma_f32_16x16x32_bf16(aF.v, bF[nt], zz, 0, 0, 0);
    }

    float tw = triw[t * 3 + 0], itw = 1.f / tw;
    float cb = crb[t * 3 + 0];
    float al = alp[t * 2 + 0];
    float apw[4] = {al * al * al * 0.25f, al * al * 0.25f, al * 0.25f, 0.25f};
    size_t imgbase = (size_t)bi * 43264;
    float* swt_w = &swt[w * 512];
    int qa = q & 1;

#pragma unroll
    for (int mt = 0; mt < 4; ++mt) {
        int tile = w * 4 + mt;
        int ty = tile / 12, tx = tile % 12;
        f32x4 xq = *(const f32x4*)&sxq[(ty * 4 + q) * 48 + tx * 4];
#pragma unroll
        for (int nt = 0; nt < 4; ++nt) {
            float hw[4];
#pragma unroll
            for (int r = 0; r < 4; ++r) {
                float d = fmaf(-2.f, acc[mt][nt][r], xq[r]) + wqv[nt];
                d = fminf(fmaxf(d, 0.f), tw);
                float h = 1.f - d * itw;
                h = (h >= cb) ? h : 0.f;
                hw[r] = h * apw[qa * 2 + (r & 1)];
            }
            swt_w[(q * 2 + 0) * 64 + nt * 16 + lm] = hw[0] + hw[1];
            swt_w[(q * 2 + 1) * 64 + nt * 16 + lm] = hw[2] + hw[3];
        }
        int cell = l >> 4;
        int py = cell >> 1, px = cell & 1;
        int ch0 = (l & 15) * 4;
        f32x4 v0 = *(const f32x4*)&swt_w[(py * 4 + px) * 64 + ch0];
        f32x4 v1 = *(const f32x4*)&swt_w[((2 * py + 1) * 2 + px) * 64 + ch0];
        f32x4 s;
#pragma unroll
        for (int j = 0; j < 4; ++j) s[j] = v0[j] + v1[j];
        uint2 uv; uv.x = pkbf(s[0], s[1]); uv.y = pkbf(s[2], s[3]);
        int py_g = qv * 6 + ty * 2 + py;
        int px_g = tx * 2 + px;
        int cell_g = (py_g + 1) * 26 + px_g + 1;
        *(uint2*)(p1u + imgbase + (size_t)cell_g * 64 + ch0) = uv;
        float r0v = bf2f((unsigned short)(uv.x & 0xFFFFu));
        float r1v = bf2f((unsigned short)(uv.x >> 16));
        float r2v = bf2f((unsigned short)(uv.y & 0xFFFFu));
        float r3v = bf2f((unsigned short)(uv.y >> 16));
        float s2p = r0v * r0v + r1v * r1v + r2v * r2v + r3v * r3v;
#pragma unroll
        for (int m2 = 1; m2 < 16; m2 <<= 1) s2p += __shfl_xor(s2p, m2, 64);
        if ((l & 15) == 0) S2[(size_t)bi * 576 + py_g * 24 + px_g] = s2p;
    }

    if (tid < 200) {
        int e = qv * 200 + tid;
        int bc = e >> 3, c8 = e & 7;
        int cell;
        if (bc < 26) cell = bc;
        else if (bc < 52) cell = 650 + (bc - 26);
        else { int r = bc - 52; cell = (1 + (r >> 1)) * 26 + ((r & 1) * 25); }
        uint4 z; z.x = 0; z.y = 0; z.z = 0; z.w = 0;
        *(uint4*)(p1u + imgbase + (size_t)cell * 64 + c8 * 8) = z;
    }
}

// ------------------------- conv2: half-image MFMA, fixed swizzle -----------
// grid (768 = 384img x 2 halves, 2 co-halves), block 576 = 9 waves.
// M=288, N=64, K=2ks x 9kk x 32ci. Swizzle slot=(q+(row>>1))&3 (conflict-free
// for stride-26 A rows and consecutive B rows). acc[2][4]=32 VGPRs, no spill.
// LDS: img [0,27648); w [27648,64512); sS 64512; sxqm 65968; swq 67120. 67376B.
__global__ __launch_bounds__(576, 5) void conv2_kernel(
        const unsigned short* __restrict__ p1u, const unsigned short* __restrict__ w2s,
        const float* __restrict__ S2, const float* __restrict__ triw,
        const float* __restrict__ crb, const float* __restrict__ alp,
        const float* __restrict__ wsq, unsigned short* __restrict__ p2u,
        float* __restrict__ S3) {
    extern __shared__ char sm[];
    float* sS   = (float*)(sm + 64512);
    float* sxqm = (float*)(sm + 65968);
    float* swq  = (float*)(sm + 67120);

    int ih = blockIdx.x;
    int i = ih >> 1, h = ih & 1;
    int t = i / 128;
    int co0 = blockIdx.y * 64;
    int tid = threadIdx.x;
    int w = tid >> 6, l = tid & 63;
    int lm = l & 15, q = l >> 4;

    for (int e = tid; e < 364; e += 576) {
        int rl = e / 26, cc = e % 26;
        int gy = 12 * h + rl - 1, gx = cc - 1;
        sS[e] = (gy >= 0 && gy < 24 && gx >= 0 && gx < 24)
                    ? S2[(size_t)i * 576 + gy * 24 + gx] : 0.f;
    }
    if (tid < 64) swq[tid] = wsq[192 + t * 128 + co0 + tid];
    __syncthreads();
    if (tid < 288) {
        int tile = tid >> 4, idx = tid & 15;
        int by = tile / 6, bx = tile % 6;
        int oy = by * 4 + (idx >> 2), ox = bx * 4 + (idx & 3);
        float s = 0.f;
#pragma unroll
        for (int ky = 0; ky < 3; ++ky)
#pragma unroll
            for (int kx = 0; kx < 3; ++kx) s += sS[(oy + ky) * 26 + ox + kx];
        sxqm[tid] = s;
    }

    int posA[2];
#pragma unroll
    for (int mt = 0; mt < 2; ++mt) {
        int tile = w * 2 + mt;
        int by = tile / 6, bx = tile % 6;
        posA[mt] = (by * 4 + (lm >> 2)) * 26 + bx * 4 + (lm & 3);
    }

    f32x4 zz; zz[0] = 0.f; zz[1] = 0.f; zz[2] = 0.f; zz[3] = 0.f;
    f32x4 acc[2][4];
#pragma unroll
    for (int a = 0; a < 2; ++a)
#pragma unroll
        for (int bb = 0; bb < 4; ++bb) acc[a][bb] = zz;

    for (int ks = 0; ks < 2; ++ks) {
        __syncthreads();
        // img: 364 cells x 4 chunks = 1456 (masked tail); slot=(pos-(cell>>1))&3
#pragma unroll
        for (int it = 0; it < 3; ++it) {
            int L = it * 576 + tid;
            if (L < 1456) {
                int cell = L >> 2, pos = L & 3;
                int c = (pos - (cell >> 1)) & 3;
                const unsigned short* g = p1u + ((size_t)i * 676 + cell + h * 312) * 64
                                          + ks * 32 + c * 8;
                async16(sm + ((L & ~63) << 4), g);
            }
        }
        // weights: 9kk x 64co x 32ci = 2304 chunks (exact)
#pragma unroll
        for (int it = 0; it < 4; ++it) {
            int L = it * 576 + tid;
            int row = L >> 2, pos = L & 3;
            int c = (pos - (row >> 1)) & 3;
            int kk = row >> 6, n = row & 63;
            const unsigned short* g = w2s + ((size_t)(t * 9 + kk) * 128 + co0 + n) * 64
                                      + ks * 32 + c * 8;
            async16(sm + 27648 + ((L & ~63) << 4), g);
        }
        __builtin_amdgcn_s_waitcnt(0);
        __syncthreads();
#pragma unroll
        for (int kk = 0; kk < 9; ++kk) {
            int kof = (kk / 3) * 26 + (kk % 3);
            bf16x8 aF2[2], bF2[4];
#pragma unroll
            for (int mt = 0; mt < 2; ++mt) {
                int ci = posA[mt] + kof;
                aF2[mt] = *(const bf16x8*)(sm + ci * 64 + ((q + (ci >> 1)) & 3) * 16);
            }
#pragma unroll
            for (int nt = 0; nt < 4; ++nt) {
                int r = kk * 64 + nt * 16 + lm;
                bF2[nt] = *(const bf16x8*)(sm + 27648 + r * 64 + ((q + (r >> 1)) & 3) * 16);
                acc[0][nt] = __builtin_amdgcn_mfma_f32_16x16x32_bf16(aF2[0], bF2[nt], acc[0][nt], 0, 0, 0);
                acc[1][nt] = __builtin_amdgcn_mfma_f32_16x16x32_bf16(aF2[1], bF2[nt], acc[1][nt], 0, 0, 0);
            }
        }
    }

    float tw = triw[t * 3 + 1], itw = 1.f / tw, cb = crb[t * 3 + 1], al = alp[t * 2 + 1];
    float apw[4] = {al * al * al * 0.25f, al * al * 0.25f, al * 0.25f, 0.25f};
    int qa = q & 1;

#pragma unroll
    for (int mt = 0; mt < 2; ++mt) {
        int tile = w * 2 + mt;
        int by = tile / 6, bx = tile % 6;
        f32x4 xq = *(const f32x4*)(sxqm + tile * 16 + q * 4);
        float s3loc[2] = {0.f, 0.f};
        unsigned short pu[4][2];
#pragma unroll
        for (int nt = 0; nt < 4; ++nt) {
            float wq = swq[nt * 16 + lm];
            float hw[4];
#pragma unroll
            for (int r = 0; r < 4; ++r) {
                float d = fmaf(-2.f, acc[mt][nt][r], xq[r]) + wq;
                d = fminf(fmaxf(d, 0.f), tw);
                float hv = 1.f - d * itw;
                hv = (hv >= cb) ? hv : 0.f;
                hw[r] = hv * apw[qa * 2 + (r & 1)];
            }
            float ph0 = hw[0] + hw[1], ph1 = hw[2] + hw[3];
            float p0 = ph0 + __shfl_xor(ph0, 16, 64);
            float p1 = ph1 + __shfl_xor(ph1, 16, 64);
            unsigned short u0 = f2bf(p0), u1 = f2bf(p1);
            float v0 = bf2f(u0), v1 = bf2f(u1);
            s3loc[0] += v0 * v0;
            s3loc[1] += v1 * v1;
            pu[nt][0] = u0; pu[nt][1] = u1;
        }
#pragma unroll
        for (int m2 = 1; m2 < 16; m2 <<= 1) {
            s3loc[0] += __shfl_xor(s3loc[0], m2, 64);
            s3loc[1] += __shfl_xor(s3loc[1], m2, 64);
        }
        if ((q & 1) == 0) {
            int py = h * 6 + by * 2 + (q >> 1);
            int px0 = bx * 2;
            int cell = (py + 1) * 14 + px0 + 1;
#pragma unroll
            for (int nt = 0; nt < 4; ++nt) {
                p2u[((size_t)i * 196 + cell) * 128 + co0 + nt * 16 + lm] = pu[nt][0];
                p2u[((size_t)i * 196 + cell + 1) * 128 + co0 + nt * 16 + lm] = pu[nt][1];
            }
            if (lm == 0) {
                atomicAdd(&S3[(size_t)i * 144 + py * 12 + px0], s3loc[0]);
                atomicAdd(&S3[(size_t)i * 144 + py * 12 + px0 + 1], s3loc[1]);
            }
        }
    }

    if (tid < 208) {
        int bc_l = tid >> 3, c8 = tid & 7;
        int bc = h * 26 + bc_l;
        int cell;
        if (bc < 14) cell = bc;
        else if (bc < 28) cell = 182 + (bc - 14);
        else { int r = bc - 28; cell = (1 + (r >> 1)) * 14 + ((r & 1) * 13); }
        uint2 z; z.x = 0; z.y = 0;
        *(uint2*)(p2u + ((size_t)i * 196 + cell) * 128 + co0 + c8 * 8) = z;
        *(uint2*)(p2u + ((size_t)i * 196 + cell) * 128 + co0 + c8 * 8 + 4) = z;
    }
}

// ------------------------- conv3: 2-img MFMA GEMM, fixed swizzle -----------
__global__ __launch_bounds__(576, 5) void conv3_kernel(
        const unsigned short* __restrict__ p2u, const unsigned short* __restrict__ w3s,
        const float* __restrict__ S3, const float* __restrict__ triw,
        const float* __restrict__ crb, const float* __restrict__ wsq,
        unsigned short* __restrict__ h3bf) {
    extern __shared__ char sm[];
    float* sS3   = (float*)(sm + 64512);
    float* sxq3  = (float*)(sm + 66080);
    float* wsqh3 = (float*)(sm + 67232);

    int g = blockIdx.x;
    int i0 = g * 2;
    int t = i0 / 128;
    int co0 = blockIdx.y * 64;
    int tid = threadIdx.x;
    int w = tid >> 6, l = tid & 63;
    int lm = l & 15, q = l >> 4;

    for (int e = tid; e < 392; e += 576) {
        int il = e / 196, cl = e % 196;
        int yy = cl / 14, xx = cl % 14;
        sS3[e] = (yy >= 1 && yy <= 12 && xx >= 1 && xx <= 12)
                     ? S3[(size_t)(i0 + il) * 144 + (yy - 1) * 12 + (xx - 1)] : 0.f;
    }
    if (tid < 64) wsqh3[tid] = wsq[576 + t * 256 + co0 + tid];
    __syncthreads();
    if (tid < 288) {
        int il = tid / 144, s = tid % 144;
        int oy = s / 12, ox = s % 12;
        float sum = 0.f;
#pragma unroll
        for (int ky = 0; ky < 3; ++ky)
#pragma unroll
            for (int kx = 0; kx < 3; ++kx)
                sum += sS3[il * 196 + (oy + ky) * 14 + (ox + kx)];
        sxq3[tid] = sum;
    }

    int posA[2], img_l[2], s0a[2];
#pragma unroll
    for (int mt = 0; mt < 2; ++mt) {
        int tb = w * 32 + mt * 16;
        int il = tb / 144, s0 = tb % 144;
        int s = s0 + lm;
        posA[mt] = il * 196 + (s / 12) * 14 + (s % 12);
        img_l[mt] = il; s0a[mt] = s0;
    }

    f32x4 zz; zz[0] = 0.f; zz[1] = 0.f; zz[2] = 0.f; zz[3] = 0.f;
    f32x4 acc[2][4];
#pragma unroll
    for (int a = 0; a < 2; ++a)
#pragma unroll
        for (int bb = 0; bb < 4; ++bb) acc[a][bb] = zz;

    for (int ks = 0; ks < 4; ++ks) {
        __syncthreads();
#pragma unroll
        for (int it = 0; it < 3; ++it) {
            int L = it * 576 + tid;
            if (L < 1568) {
                int cell = L >> 2, pos = L & 3;
                int il = cell / 196, cl = cell - il * 196;
                int c = (pos - (cell >> 1)) & 3;
                const unsigned short* gp = p2u + ((size_t)(i0 + il) * 196 + cl) * 128
                                           + ks * 32 + c * 8;
                async16(sm + ((L & ~63) << 4), gp);
            }
        }
#pragma unroll
        for (int it = 0; it < 4; ++it) {
            int L = it * 576 + tid;
            int row = L >> 2, pos = L & 3;
            int c = (pos - (row >> 1)) & 3;
            int kk = row >> 6, n = row & 63;
            const unsigned short* gp = w3s + ((size_t)(t * 9 + kk) * 256 + co0 + n) * 128
                                       + ks * 32 + c * 8;
            async16(sm + 27648 + ((L & ~63) << 4), gp);
        }
        __builtin_amdgcn_s_waitcnt(0);
        __syncthreads();
#pragma unroll
        for (int kk = 0; kk < 9; ++kk) {
            int kof = (kk / 3) * 14 + (kk % 3);
            bf16x8 aF3[2], bF3[4];
#pragma unroll
            for (int mt = 0; mt < 2; ++mt) {
                int ci = posA[mt] + kof;
                aF3[mt] = *(const bf16x8*)(sm + ci * 64 + ((q + (ci >> 1)) & 3) * 16);
            }
#pragma unroll
            for (int nt = 0; nt < 4; ++nt) {
                int r = kk * 64 + nt * 16 + lm;
                bF3[nt] = *(const bf16x8*)(sm + 27648 + r * 64 + ((q + (r >> 1)) & 3) * 16);
                acc[0][nt] = __builtin_amdgcn_mfma_f32_16x16x32_bf16(aF3[0], bF3[nt], acc[0][nt], 0, 0, 0);
                acc[1][nt] = __builtin_amdgcn_mfma_f32_16x16x32_bf16(aF3[1], bF3[nt], acc[1][nt], 0, 0, 0);
            }
        }
    }
    __syncthreads();

    float tw = triw[t * 3 + 2], itw = 1.f / tw, cb = crb[t * 3 + 2];
    float* tile = (float*)(sm + w * 1280);
#pragma unroll
    for (int mt = 0; mt < 2; ++mt) {
        int il = img_l[mt], s0 = s0a[mt];
        int bidx = (i0 + il) - t * 128;
        unsigned short* gbase = h3bf + (size_t)bidx * 110592 + (size_t)t * 36864;
#pragma unroll
        for (int nt = 0; nt < 4; ++nt) {
            float wq = wsqh3[nt * 16 + lm];
#pragma unroll
            for (int r = 0; r < 4; ++r) {
                float d = sxq3[il * 144 + s0 + q * 4 + r] - 2.f * acc[mt][nt][r] + wq;
                d = fminf(fmaxf(d, 0.f), tw);
                float hv = 1.f - d * itw;
                hv = (hv >= cb) ? hv : 0.f;
                tile[lm * 20 + q * 4 + r] = hv;
            }
            f32x4 v = *(const f32x4*)(tile + (l >> 2) * 20 + (l & 3) * 4);
            uint2 uv; uv.x = pkbf(v[0], v[1]); uv.y = pkbf(v[2], v[3]);
            *(uint2*)(gbase + (size_t)(co0 + nt * 16 + (l >> 2)) * 144 + s0 + (l & 3) * 4) = uv;
        }
    }
}

// ------------------------- FC: LDS-free bf16 MFMA K-split ------------------
__global__ __launch_bounds__(512) void fc_kernel(
        const unsigned short* __restrict__ h3bf, const float* __restrict__ fcw,
        float* __restrict__ part) {
    int kb = blockIdx.x;
    int f0 = kb * 256;
    int tid = threadIdx.x;
    int w = tid >> 6, l = tid & 63;
    int lm = l & 15, q = l >> 4;

    const unsigned short* abase = h3bf + (size_t)(w * 16 + lm) * 110592 + f0 + q * 8;
    const float* brow[7];
#pragma unroll
    for (int nt = 0; nt < 7; ++nt) {
        int n = nt * 16 + lm;
        if (n > 99) n = 99;
        brow[nt] = fcw + (size_t)n * 110592 + f0 + q * 8;
    }

    f32x4 zz; zz[0] = 0.f; zz[1] = 0.f; zz[2] = 0.f; zz[3] = 0.f;
    f32x4 acc[7];
#pragma unroll
    for (int nt = 0; nt < 7; ++nt) acc[nt] = zz;

#pragma unroll 2
    for (int kc = 0; kc < 8; ++kc) {
        bf16x8 aF = *(const bf16x8*)(abase + kc * 32);
#pragma unroll
        for (int nt = 0; nt < 7; ++nt) {
            f32x4 b0 = *(const f32x4*)(brow[nt] + kc * 32);
            f32x4 b1 = *(const f32x4*)(brow[nt] + kc * 32 + 4);
            union { bf16x8 v; unsigned u[4]; } bF;
            bF.u[0] = pkbf(b0[0], b0[1]);
            bF.u[1] = pkbf(b0[2], b0[3]);
            bF.u[2] = pkbf(b1[0], b1[1]);
            bF.u[3] = pkbf(b1[2], b1[3]);
            acc[nt] = __builtin_amdgcn_mfma_f32_16x16x32_bf16(aF, bF.v, acc[nt], 0, 0, 0);
        }
    }

    float* pb = part + (size_t)kb * 14336;
#pragma unroll
    for (int nt = 0; nt < 7; ++nt)
#pragma unroll
        for (int r = 0; r < 4; ++r)
            pb[(w * 16 + q * 4 + r) * 112 + nt * 16 + lm] = acc[nt][r];
}

__global__ __launch_bounds__(256) void fc_red1_kernel(const float* __restrict__ part,
                                                      float* __restrict__ part2) {
    int c = blockIdx.x;
    int gid = blockIdx.y * 256 + threadIdx.x;
    if (gid >= 12800) return;
    const float* p = part + (size_t)(c * 54) * 14336 + (gid / 100) * 112 + gid % 100;
    float s = 0.f;
#pragma unroll 6
    for (int kb = 0; kb < 54; ++kb) s += p[(size_t)kb * 14336];
    part2[c * 12800 + gid] = s;
}

__global__ __launch_bounds__(256) void fc_red2_kernel(const float* __restrict__ part2,
                                                      const float* __restrict__ fcb,
                                                      float* __restrict__ out) {
    int gid = blockIdx.x * 256 + threadIdx.x;
    if (gid >= 12800) return;
    float s = fcb[gid % 100];
#pragma unroll
    for (int c = 0; c < 8; ++c) s += part2[c * 12800 + gid];
    out[gid] = s;
}

// ---------------------------------------------------------------------------
extern "C" void kernel_launch(void* const* d_in, const int* in_sizes, int n_in,
                              void* d_out, int out_size, void* d_ws, size_t ws_size,
                              hipStream_t stream) {
    const float* x    = (const float*)d_in[0];
    const float* W1   = (const float*)d_in[1];
    const float* W2   = (const float*)d_in[2];
    const float* W3   = (const float*)d_in[3];
    const float* triw = (const float*)d_in[4];
    const float* crb  = (const float*)d_in[5];
    const float* alp  = (const float*)d_in[6];
    const float* fcw  = (const float*)d_in[7];
    const float* fcb  = (const float*)d_in[8];
    float* out = (float*)d_out;
    float* ws  = (float*)d_ws;

    unsigned short* p1u = (unsigned short*)ws;
    unsigned short* p2u = (unsigned short*)(ws + OFF_P2CL);
    float* S2  = ws + OFF_S2;
    float* S3  = ws + OFF_S3;
    float* wsq = ws + OFF_WSQ;
    unsigned short* w2s = (unsigned short*)(ws + OFF_W2S);
    unsigned short* w3s = (unsigned short*)(ws + OFF_W3S);
    float* part  = ws + OFF_PART;
    float* part2 = ws + OFF_PART2;
    unsigned short* h3bf = (unsigned short*)ws;

    hipFuncSetAttribute((const void*)conv2_kernel,
                        hipFuncAttributeMaxDynamicSharedMemorySize, 67376);
    hipFuncSetAttribute((const void*)conv3_kernel,
                        hipFuncAttributeMaxDynamicSharedMemorySize, 67488);

    prep_kernel<<<dim3(432), dim3(256), 0, stream>>>(W2, W3, w2s, w3s, wsq, S3);
    conv1_kernel<<<dim3(384, 4), dim3(576), 0, stream>>>(x, W1, triw, crb, alp, p1u, S2);
    conv2_kernel<<<dim3(768, 2), dim3(576), 67376, stream>>>(p1u, w2s, S2, triw, crb, alp, wsq, p2u, S3);
    conv3_kernel<<<dim3(192, 4), dim3(576), 67488, stream>>>(p2u, w3s, S3, triw, crb, wsq, h3bf);
    fc_kernel<<<dim3(432), dim3(512), 0, stream>>>(h3bf, fcw, part);
    fc_red1_kernel<<<dim3(8, 50), dim3(256), 0, stream>>>(part, part2);
    fc_red2_kernel<<<dim3(50), dim3(256), 0, stream>>>(part2, fcb, out);
}